// Round 13
// baseline (1040.404 us; speedup 1.0000x reference)
//
#include <hip/hip_runtime.h>

typedef __attribute__((ext_vector_type(8))) short bf16x8;
typedef __attribute__((ext_vector_type(4))) float f32x4;
typedef __attribute__((ext_vector_type(4))) unsigned short us4;
typedef __attribute__((ext_vector_type(8))) unsigned short us8;

static __device__ __forceinline__ float bf2f(unsigned short u) {
    union { unsigned int i; float f; } cv; cv.i = ((unsigned int)u) << 16;
    return cv.f;
}
static __device__ __forceinline__ unsigned short f2bf(float f) {
    union { float f; unsigned int i; } cv; cv.f = f;
    unsigned int x = cv.i;
    unsigned int lsb = (x >> 16) & 1u;
    x += 0x7fffu + lsb;
    return (unsigned short)(x >> 16);
}

// async global->LDS, 16B per lane; LDS dest is wave-uniform base + lane*16
static __device__ __forceinline__ void gload16(const void* g, void* l) {
    __builtin_amdgcn_global_load_lds(
        (const __attribute__((address_space(1))) void*)g,
        (__attribute__((address_space(3))) void*)l, 16, 0, 0);
}

// ---------------- zero (hipMemsetAsync's runtime fill kernel writes 819MB) ----------------
__global__ __launch_bounds__(256) void k_zero(int* __restrict__ p, int n) {
    int i = blockIdx.x * 256 + threadIdx.x;
    if (i < n) p[i] = 0;
}

// ---------------- CSR build ----------------
__global__ __launch_bounds__(256) void k_hist(const int* __restrict__ dst,
                                              int* __restrict__ cnt, int E) {
    int i = blockIdx.x * 256 + threadIdx.x;
    if (i < E) atomicAdd(&cnt[dst[i]], 1);
}

__global__ __launch_bounds__(256) void k_bsum(const int* __restrict__ cnt,
                                              int* __restrict__ bsum, int M) {
    __shared__ int sm[256];
    int t = threadIdx.x;
    int base = blockIdx.x * 1024 + t * 4;
    int s = 0;
#pragma unroll
    for (int j = 0; j < 4; ++j) {
        int i = base + j;
        if (i < M) s += cnt[i];
    }
    sm[t] = s;
    __syncthreads();
    for (int off = 128; off; off >>= 1) {
        if (t < off) sm[t] += sm[t + off];
        __syncthreads();
    }
    if (t == 0) bsum[blockIdx.x] = sm[0];
}

// parallel exclusive scan of bsum (NB <= 256)
__global__ __launch_bounds__(256) void k_scanb(int* __restrict__ bsum, int NB,
                                               int* __restrict__ rowptr, int M, int E) {
    __shared__ int sm[256];
    int t = threadIdx.x;
    int v = (t < NB) ? bsum[t] : 0;
    sm[t] = v;
    __syncthreads();
    for (int off = 1; off < 256; off <<= 1) {
        int u = (t >= off) ? sm[t - off] : 0;
        __syncthreads();
        sm[t] += u;
        __syncthreads();
    }
    if (t < NB) bsum[t] = sm[t] - v;   // exclusive
    if (t == 0) rowptr[M] = E;
}

__global__ __launch_bounds__(256) void k_rowptr(const int* __restrict__ cnt,
                                                const int* __restrict__ bsum,
                                                int* __restrict__ rowptr,
                                                int* __restrict__ cursor, int M) {
    __shared__ int sm[256];
    int t = threadIdx.x;
    int base = blockIdx.x * 1024 + t * 4;
    int c[4];
    int ts = 0;
#pragma unroll
    for (int j = 0; j < 4; ++j) {
        int i = base + j;
        c[j] = (i < M) ? cnt[i] : 0;
        ts += c[j];
    }
    sm[t] = ts;
    __syncthreads();
    for (int off = 1; off < 256; off <<= 1) {
        int v = (t >= off) ? sm[t - off] : 0;
        __syncthreads();
        sm[t] += v;
        __syncthreads();
    }
    int ex = bsum[blockIdx.x] + sm[t] - ts;
#pragma unroll
    for (int j = 0; j < 4; ++j) {
        int i = base + j;
        if (i < M) {
            rowptr[i] = ex;
            cursor[i] = ex;
        }
        ex += c[j];
    }
}

__global__ __launch_bounds__(256) void k_place(const int* __restrict__ src,
                                               const int* __restrict__ dst,
                                               int* __restrict__ cursor,
                                               int* __restrict__ eidx, int E) {
    int i = blockIdx.x * 256 + threadIdx.x;
    if (i < E) {
        int slot = atomicAdd(&cursor[dst[i]], 1);
        eidx[slot] = src[i];
    }
}

// ---------------- f32 -> bf16 row-major convert ----------------
__global__ __launch_bounds__(256) void k_convx(const float* __restrict__ x,
                                               unsigned short* __restrict__ xb, int n8) {
    int i = blockIdx.x * 256 + threadIdx.x;
    if (i >= n8) return;
    const f32x4* p = (const f32x4*)(x + (size_t)i * 8);
    f32x4 u0 = p[0], u1 = p[1];
    union { us8 v; unsigned short u[8]; } tmp;
    tmp.u[0] = f2bf(u0.x); tmp.u[1] = f2bf(u0.y);
    tmp.u[2] = f2bf(u0.z); tmp.u[3] = f2bf(u0.w);
    tmp.u[4] = f2bf(u1.x); tmp.u[5] = f2bf(u1.y);
    tmp.u[6] = f2bf(u1.z); tmp.u[7] = f2bf(u1.w);
    *(us8*)(xb + (size_t)i * 8) = tmp.v;
}

// ---------------- pull aggregation: mean over neighbors ----------------
// half-wave (32 lanes) per row, us8 16-B loads; 2-way edge unroll for MLP.
__global__ __launch_bounds__(256) void k_gather_mean(const unsigned short* __restrict__ xsrc,
                                                     const int* __restrict__ rowptr,
                                                     const int* __restrict__ eidx,
                                                     unsigned short* __restrict__ mean, int M) {
    int r = blockIdx.x * 8 + (threadIdx.x >> 5);
    if (r >= M) return;
    int g = threadIdx.x & 31;
    int s0 = rowptr[r], s1 = rowptr[r + 1];
    float a[8];
#pragma unroll
    for (int j = 0; j < 8; ++j) a[j] = 0.f;
    int e = s0;
    for (; e + 2 <= s1; e += 2) {
        int sA = eidx[e], sB = eidx[e + 1];
        union { us8 v; unsigned short u[8]; } vA, vB;
        vA.v = *(const us8*)(xsrc + (size_t)sA * 256 + g * 8);
        vB.v = *(const us8*)(xsrc + (size_t)sB * 256 + g * 8);
#pragma unroll
        for (int j = 0; j < 8; ++j) a[j] += bf2f(vA.u[j]) + bf2f(vB.u[j]);
    }
    if (e < s1) {
        int sA = eidx[e];
        union { us8 v; unsigned short u[8]; } vA;
        vA.v = *(const us8*)(xsrc + (size_t)sA * 256 + g * 8);
#pragma unroll
        for (int j = 0; j < 8; ++j) a[j] += bf2f(vA.u[j]);
    }
    float rinv = (s1 > s0) ? 1.0f / (float)(s1 - s0) : 0.0f;
    union { us8 v; unsigned short u[8]; } o;
#pragma unroll
    for (int j = 0; j < 8; ++j) o.u[j] = f2bf(a[j] * rinv);
    *(us8*)(mean + (size_t)r * 256 + g * 8) = o.v;
}

// ---------------- weight conversion into K-tiled fragment order ----------------
__global__ __launch_bounds__(256) void k_convw(const float* __restrict__ Wl,
                                               const float* __restrict__ Wr,
                                               const float* __restrict__ fcW,
                                               unsigned short* __restrict__ Wc1,
                                               unsigned short* __restrict__ Wc2,
                                               unsigned short* __restrict__ fcWb) {
    int idx = blockIdx.x * 256 + threadIdx.x;
    if (idx < 262144) {
        int layer = idx >> 17;
        int i = idx & 131071;
        int kt = i >> 14;
        int sub = (i >> 10) & 15;
        int kk = (i >> 9) & 1;
        int sl = (i >> 3) & 63;
        int e = i & 7;
        int n = sub * 16 + (sl & 15);
        int k = kt * 64 + kk * 32 + (sl >> 4) * 8 + e;
        int base = layer * 196608;
        float v = (k < 256) ? Wl[base + n * 256 + k] : Wr[base + n * 256 + (k - 256)];
        (layer ? Wc2 : Wc1)[i] = f2bf(v);
    } else {
        int i = idx - 262144;
        if (i < 32768) {
            int kt = i >> 13;
            int sub = (i >> 10) & 7;
            int kk = (i >> 9) & 1;
            int sl = (i >> 3) & 63;
            int e = i & 7;
            int n = sub * 16 + (sl & 15);
            int k = kt * 64 + kk * 32 + (sl >> 4) * 8 + e;
            fcWb[i] = f2bf(fcW[n * 256 + k]);
        }
    }
}

// ---------------- layer-1 GEMM: h = relu([mean | xs] @ Wc^T + bias) ----------------
// R12 structure; occupancy raised to 6 blocks/CU (VGPR cap 85 >= 68 used; LDS 24KB*6=144KB).
__global__ __launch_bounds__(256, 6) void k_sage_gemm(const unsigned short* __restrict__ meanb,
                                                      const unsigned short* __restrict__ xs,
                                                      const unsigned short* __restrict__ Wct,
                                                      const float* __restrict__ bias,
                                                      unsigned short* __restrict__ out, int M) {
    __shared__ __align__(16) unsigned short Asm[3][4096];   // 64 rows x 64 k, frag-major
    const int t = threadIdx.x;
    const int w = t >> 6, l = t & 63;
    const int lrow = l & 15, slot = l >> 4;
    const int row0 = blockIdx.x * 64;

    int a_row = row0 + w * 16 + lrow;
    if (a_row > M - 1) a_row = M - 1;
    const size_t a_base = (size_t)a_row * 256 + slot * 8;

    f32x4 acc[4][4];
#pragma unroll
    for (int n = 0; n < 4; ++n)
#pragma unroll
        for (int m = 0; m < 4; ++m)
#pragma unroll
            for (int j = 0; j < 4; ++j) acc[n][m][j] = 0.0f;

    auto stageA = [&](int bb, int kt) {
        const unsigned short* src = (kt < 4) ? meanb + a_base + kt * 64
                                             : xs + a_base + (kt - 4) * 64;
        gload16(src,      &Asm[bb][w * 1024]);
        gload16(src + 32, &Asm[bb][w * 1024 + 512]);
    };
    bf16x8 bfr[4][2];
    auto loadB = [&](int kt) {
#pragma unroll
        for (int m = 0; m < 4; ++m)
#pragma unroll
            for (int kk = 0; kk < 2; ++kk)
                bfr[m][kk] = *(const bf16x8*)(Wct + (size_t)kt * 16384
                                              + (size_t)(w * 4 + m) * 1024 + kk * 512 + l * 8);
    };

    stageA(0, 0);
    stageA(1, 1);
    loadB(0);

    bf16x8 af[4];
#pragma unroll
    for (int kt = 0; kt < 8; ++kt) {
        const int cb = kt % 3;
        if (kt < 7) { asm volatile("s_waitcnt vmcnt(10)" ::: "memory"); }
        else        { asm volatile("s_waitcnt vmcnt(8)"  ::: "memory"); }
        __builtin_amdgcn_s_barrier();
        __builtin_amdgcn_sched_barrier(0);
        if (kt < 6) stageA((kt + 2) % 3, kt + 2);
#pragma unroll
        for (int kk = 0; kk < 2; ++kk) {
#pragma unroll
            for (int n = 0; n < 4; ++n)
                af[n] = *(const bf16x8*)(&Asm[cb][n * 1024 + kk * 512 + l * 8]);
            __builtin_amdgcn_s_setprio(1);
#pragma unroll
            for (int n = 0; n < 4; ++n)
#pragma unroll
                for (int m = 0; m < 4; ++m)
                    acc[n][m] = __builtin_amdgcn_mfma_f32_16x16x32_bf16(bfr[m][kk], af[n], acc[n][m], 0, 0, 0);
            __builtin_amdgcn_s_setprio(0);
        }
        __builtin_amdgcn_sched_barrier(0);
        if (kt < 7) loadB(kt + 1);   // bottom-of-iter B prefetch (bfr regs now free)
        asm volatile("s_waitcnt lgkmcnt(0)" ::: "memory");
    }

#pragma unroll
    for (int n = 0; n < 4; ++n) {
        const int grow = row0 + n * 16 + lrow;
        if (grow >= M) continue;
#pragma unroll
        for (int m = 0; m < 4; ++m) {
            const int gcol = w * 64 + m * 16 + slot * 4;
            f32x4 bv = *(const f32x4*)(bias + gcol);
            us4 o;
            o.x = f2bf(fmaxf(acc[n][m][0] + bv.x, 0.f));
            o.y = f2bf(fmaxf(acc[n][m][1] + bv.y, 0.f));
            o.z = f2bf(fmaxf(acc[n][m][2] + bv.z, 0.f));
            o.w = f2bf(fmaxf(acc[n][m][3] + bv.w, 0.f));
            *(us4*)(out + (size_t)grow * 256 + gcol) = o;
        }
    }
}

// ---------------- FUSED layer-2 + fc: out = relu([mean|h]@Wc2^T + bl) @ fcW^T + fcb ----
// R12 structure; occupancy raised to 4 blocks/CU (32KB pool -> 128KB LDS; VGPR cap 128).
__global__ __launch_bounds__(256, 4) void k_sage_fc_gemm(const unsigned short* __restrict__ meanb,
                                                         const unsigned short* __restrict__ xs,
                                                         const unsigned short* __restrict__ Wct,
                                                         const float* __restrict__ bias,
                                                         const unsigned short* __restrict__ fcWbt,
                                                         const float* __restrict__ fcb,
                                                         float* __restrict__ out, int M) {
    __shared__ __align__(16) unsigned short pool[16384];   // 32 KB; tri-buffer aliases first 24 KB
    unsigned short (*Asm)[4096] = (unsigned short(*)[4096])pool;
    const int t = threadIdx.x;
    const int w = t >> 6, l = t & 63;
    const int lrow = l & 15, slot = l >> 4;
    const int row0 = blockIdx.x * 64;

    int a_row = row0 + w * 16 + lrow;
    if (a_row > M - 1) a_row = M - 1;
    const size_t a_base = (size_t)a_row * 256 + slot * 8;

    f32x4 acc[4][4];
#pragma unroll
    for (int n = 0; n < 4; ++n)
#pragma unroll
        for (int m = 0; m < 4; ++m)
#pragma unroll
            for (int j = 0; j < 4; ++j) acc[n][m][j] = 0.0f;

    auto stageA = [&](int bb, int kt) {
        const unsigned short* src = (kt < 4) ? meanb + a_base + kt * 64
                                             : xs + a_base + (kt - 4) * 64;
        gload16(src,      &Asm[bb][w * 1024]);
        gload16(src + 32, &Asm[bb][w * 1024 + 512]);
    };
    bf16x8 bfr[4][2];
    auto loadB = [&](int kt) {
#pragma unroll
        for (int m = 0; m < 4; ++m)
#pragma unroll
            for (int kk = 0; kk < 2; ++kk)
                bfr[m][kk] = *(const bf16x8*)(Wct + (size_t)kt * 16384
                                              + (size_t)(w * 4 + m) * 1024 + kk * 512 + l * 8);
    };

    stageA(0, 0);
    stageA(1, 1);
    loadB(0);

    bf16x8 af[4];
#pragma unroll
    for (int kt = 0; kt < 8; ++kt) {
        const int cb = kt % 3;
        if (kt < 7) { asm volatile("s_waitcnt vmcnt(10)" ::: "memory"); }
        else        { asm volatile("s_waitcnt vmcnt(8)"  ::: "memory"); }
        __builtin_amdgcn_s_barrier();
        __builtin_amdgcn_sched_barrier(0);
        if (kt < 6) stageA((kt + 2) % 3, kt + 2);
#pragma unroll
        for (int kk = 0; kk < 2; ++kk) {
#pragma unroll
            for (int n = 0; n < 4; ++n)
                af[n] = *(const bf16x8*)(&Asm[cb][n * 1024 + kk * 512 + l * 8]);
            __builtin_amdgcn_s_setprio(1);
#pragma unroll
            for (int n = 0; n < 4; ++n)
#pragma unroll
                for (int m = 0; m < 4; ++m)
                    acc[n][m] = __builtin_amdgcn_mfma_f32_16x16x32_bf16(bfr[m][kk], af[n], acc[n][m], 0, 0, 0);
            __builtin_amdgcn_s_setprio(0);
        }
        __builtin_amdgcn_sched_barrier(0);
        if (kt < 7) loadB(kt + 1);   // bottom-of-iter B prefetch
        asm volatile("s_waitcnt lgkmcnt(0)" ::: "memory");
    }

    // g = relu(acc + bias) -> bf16 -> pool (frag-major, conflict-free)
    __syncthreads();
#pragma unroll
    for (int n = 0; n < 4; ++n) {
#pragma unroll
        for (int m = 0; m < 4; ++m) {
            const int gcol = w * 64 + m * 16 + slot * 4;
            f32x4 bv = *(const f32x4*)(bias + gcol);
            us4 o;
            o.x = f2bf(fmaxf(acc[n][m][0] + bv.x, 0.f));
            o.y = f2bf(fmaxf(acc[n][m][1] + bv.y, 0.f));
            o.z = f2bf(fmaxf(acc[n][m][2] + bv.z, 0.f));
            o.w = f2bf(fmaxf(acc[n][m][3] + bv.w, 0.f));
            int addr = w * 4096 + n * 1024 + (m >> 1) * 512
                     + ((((m & 1) * 2 + (slot >> 1)) * 16 + lrow) * 8) + (slot & 1) * 4;
            *(us4*)(&pool[addr]) = o;
        }
    }
    __syncthreads();

    // fc mini-GEMM: out[64x128] = g @ fcW^T + fcb
    f32x4 acc2[4][2];
#pragma unroll
    for (int n = 0; n < 4; ++n)
#pragma unroll
        for (int m = 0; m < 2; ++m)
#pragma unroll
            for (int j = 0; j < 4; ++j) acc2[n][m][j] = 0.0f;

#pragma unroll
    for (int kt2 = 0; kt2 < 4; ++kt2) {
        bf16x8 bw[2][2];
#pragma unroll
        for (int m = 0; m < 2; ++m)
#pragma unroll
            for (int kk = 0; kk < 2; ++kk)
                bw[m][kk] = *(const bf16x8*)(fcWbt + (size_t)kt2 * 8192
                                             + (size_t)(w * 2 + m) * 1024 + kk * 512 + l * 8);
#pragma unroll
        for (int kk = 0; kk < 2; ++kk) {
            bf16x8 ag[4];
#pragma unroll
            for (int n = 0; n < 4; ++n)
                ag[n] = *(const bf16x8*)(&pool[kt2 * 4096 + n * 1024 + kk * 512 + l * 8]);
#pragma unroll
            for (int n = 0; n < 4; ++n)
#pragma unroll
                for (int m = 0; m < 2; ++m)
                    acc2[n][m] = __builtin_amdgcn_mfma_f32_16x16x32_bf16(bw[m][kk], ag[n], acc2[n][m], 0, 0, 0);
        }
    }

#pragma unroll
    for (int n = 0; n < 4; ++n) {
        const int grow = row0 + n * 16 + lrow;
        if (grow >= M) continue;
#pragma unroll
        for (int m = 0; m < 2; ++m) {
            const int gcol = w * 32 + m * 16 + slot * 4;
            f32x4 bv = *(const f32x4*)(fcb + gcol);
            f32x4 o;
            o.x = acc2[n][m][0] + bv.x;
            o.y = acc2[n][m][1] + bv.y;
            o.z = acc2[n][m][2] + bv.z;
            o.w = acc2[n][m][3] + bv.w;
            *(f32x4*)(out + (size_t)grow * 128 + gcol) = o;
        }
    }
}

extern "C" void kernel_launch(void* const* d_in, const int* in_sizes, int n_in,
                              void* d_out, int out_size, void* d_ws, size_t ws_size,
                              hipStream_t stream) {
    const float* x_word = (const float*)d_in[0];
    const float* Wl  = (const float*)d_in[3];
    const float* bl  = (const float*)d_in[4];
    const float* Wr  = (const float*)d_in[5];
    const float* fcW = (const float*)d_in[6];
    const float* fcb = (const float*)d_in[7];
    const int* src = (const int*)d_in[8];
    const int* dst = (const int*)d_in[9];

    const int M = in_sizes[0] / 256;   // 200000
    const int E = in_sizes[8];         // 400000
    const int NB = (M + 1023) / 1024;

    char* ws = (char*)d_ws;
    size_t off = 0;
    auto alloc = [&](size_t bytes) {
        void* p = ws + off;
        off = (off + bytes + 255) & ~(size_t)255;
        return p;
    };
    int* cnt_i  = (int*)alloc((size_t)M * 4);
    int* rowptr = (int*)alloc((size_t)(M + 1) * 4);
    int* cursor = (int*)alloc((size_t)M * 4);
    int* eidx   = (int*)alloc((size_t)E * 4);
    int* bsum   = (int*)alloc((size_t)NB * 4);
    unsigned short* xb    = (unsigned short*)alloc((size_t)M * 256 * 2);
    unsigned short* meanb = (unsigned short*)alloc((size_t)M * 256 * 2);
    unsigned short* h     = (unsigned short*)alloc((size_t)M * 256 * 2);
    unsigned short* Wc1   = (unsigned short*)alloc(131072 * 2);
    unsigned short* Wc2   = (unsigned short*)alloc(131072 * 2);
    unsigned short* fcWb  = (unsigned short*)alloc(32768 * 2);

    // CSR build
    k_zero<<<(M + 255) / 256, 256, 0, stream>>>(cnt_i, M);
    k_hist<<<(E + 255) / 256, 256, 0, stream>>>(dst, cnt_i, E);
    k_bsum<<<NB, 256, 0, stream>>>(cnt_i, bsum, M);
    k_scanb<<<1, 256, 0, stream>>>(bsum, NB, rowptr, M, E);
    k_rowptr<<<NB, 256, 0, stream>>>(cnt_i, bsum, rowptr, cursor, M);
    k_place<<<(E + 255) / 256, 256, 0, stream>>>(src, dst, cursor, eidx, E);

    // weights (tiled) + x -> bf16 (row-major)
    k_convw<<<1152, 256, 0, stream>>>(Wl, Wr, fcW, Wc1, Wc2, fcWb);
    k_convx<<<(M * 256 / 8 + 255) / 256, 256, 0, stream>>>(x_word, xb, M * 256 / 8);

    const int GB = (M + 63) / 64;

    // Layer 1
    k_gather_mean<<<(M + 7) / 8, 256, 0, stream>>>(xb, rowptr, eidx, meanb, M);
    k_sage_gemm<<<GB, 256, 0, stream>>>(meanb, xb, Wc1, bl, h, M);

    // Layer 2 + fc head, fused
    k_gather_mean<<<(M + 7) / 8, 256, 0, stream>>>(h, rowptr, eidx, meanb, M);
    k_sage_fc_gemm<<<GB, 256, 0, stream>>>(meanb, h, Wc2, bl + 3 * 256, fcWb, fcb,
                                           (float*)d_out, M);
}

// Round 14
// 444.098 us; speedup vs baseline: 2.3427x; 2.3427x over previous
//
#include <hip/hip_runtime.h>

typedef __attribute__((ext_vector_type(8))) short bf16x8;
typedef __attribute__((ext_vector_type(4))) float f32x4;
typedef __attribute__((ext_vector_type(4))) unsigned short us4;
typedef __attribute__((ext_vector_type(8))) unsigned short us8;

static __device__ __forceinline__ float bf2f(unsigned short u) {
    union { unsigned int i; float f; } cv; cv.i = ((unsigned int)u) << 16;
    return cv.f;
}
static __device__ __forceinline__ unsigned short f2bf(float f) {
    union { float f; unsigned int i; } cv; cv.f = f;
    unsigned int x = cv.i;
    unsigned int lsb = (x >> 16) & 1u;
    x += 0x7fffu + lsb;
    return (unsigned short)(x >> 16);
}

// async global->LDS, 16B per lane; LDS dest is wave-uniform base + lane*16
static __device__ __forceinline__ void gload16(const void* g, void* l) {
    __builtin_amdgcn_global_load_lds(
        (const __attribute__((address_space(1))) void*)g,
        (__attribute__((address_space(3))) void*)l, 16, 0, 0);
}

// ---------------- zero (hipMemsetAsync's runtime fill kernel writes 819MB) ----------------
__global__ __launch_bounds__(256) void k_zero(int* __restrict__ p, int n) {
    int i = blockIdx.x * 256 + threadIdx.x;
    if (i < n) p[i] = 0;
}

// ---------------- CSR build ----------------
__global__ __launch_bounds__(256) void k_hist(const int* __restrict__ dst,
                                              int* __restrict__ cnt, int E) {
    int i = blockIdx.x * 256 + threadIdx.x;
    if (i < E) atomicAdd(&cnt[dst[i]], 1);
}

__global__ __launch_bounds__(256) void k_bsum(const int* __restrict__ cnt,
                                              int* __restrict__ bsum, int M) {
    __shared__ int sm[256];
    int t = threadIdx.x;
    int base = blockIdx.x * 1024 + t * 4;
    int s = 0;
#pragma unroll
    for (int j = 0; j < 4; ++j) {
        int i = base + j;
        if (i < M) s += cnt[i];
    }
    sm[t] = s;
    __syncthreads();
    for (int off = 128; off; off >>= 1) {
        if (t < off) sm[t] += sm[t + off];
        __syncthreads();
    }
    if (t == 0) bsum[blockIdx.x] = sm[0];
}

// parallel exclusive scan of bsum (NB <= 256)
__global__ __launch_bounds__(256) void k_scanb(int* __restrict__ bsum, int NB,
                                               int* __restrict__ rowptr, int M, int E) {
    __shared__ int sm[256];
    int t = threadIdx.x;
    int v = (t < NB) ? bsum[t] : 0;
    sm[t] = v;
    __syncthreads();
    for (int off = 1; off < 256; off <<= 1) {
        int u = (t >= off) ? sm[t - off] : 0;
        __syncthreads();
        sm[t] += u;
        __syncthreads();
    }
    if (t < NB) bsum[t] = sm[t] - v;   // exclusive
    if (t == 0) rowptr[M] = E;
}

__global__ __launch_bounds__(256) void k_rowptr(const int* __restrict__ cnt,
                                                const int* __restrict__ bsum,
                                                int* __restrict__ rowptr,
                                                int* __restrict__ cursor, int M) {
    __shared__ int sm[256];
    int t = threadIdx.x;
    int base = blockIdx.x * 1024 + t * 4;
    int c[4];
    int ts = 0;
#pragma unroll
    for (int j = 0; j < 4; ++j) {
        int i = base + j;
        c[j] = (i < M) ? cnt[i] : 0;
        ts += c[j];
    }
    sm[t] = ts;
    __syncthreads();
    for (int off = 1; off < 256; off <<= 1) {
        int v = (t >= off) ? sm[t - off] : 0;
        __syncthreads();
        sm[t] += v;
        __syncthreads();
    }
    int ex = bsum[blockIdx.x] + sm[t] - ts;
#pragma unroll
    for (int j = 0; j < 4; ++j) {
        int i = base + j;
        if (i < M) {
            rowptr[i] = ex;
            cursor[i] = ex;
        }
        ex += c[j];
    }
}

__global__ __launch_bounds__(256) void k_place(const int* __restrict__ src,
                                               const int* __restrict__ dst,
                                               int* __restrict__ cursor,
                                               int* __restrict__ eidx, int E) {
    int i = blockIdx.x * 256 + threadIdx.x;
    if (i < E) {
        int slot = atomicAdd(&cursor[dst[i]], 1);
        eidx[slot] = src[i];
    }
}

// ---------------- f32 -> bf16 row-major convert ----------------
__global__ __launch_bounds__(256) void k_convx(const float* __restrict__ x,
                                               unsigned short* __restrict__ xb, int n8) {
    int i = blockIdx.x * 256 + threadIdx.x;
    if (i >= n8) return;
    const f32x4* p = (const f32x4*)(x + (size_t)i * 8);
    f32x4 u0 = p[0], u1 = p[1];
    union { us8 v; unsigned short u[8]; } tmp;
    tmp.u[0] = f2bf(u0.x); tmp.u[1] = f2bf(u0.y);
    tmp.u[2] = f2bf(u0.z); tmp.u[3] = f2bf(u0.w);
    tmp.u[4] = f2bf(u1.x); tmp.u[5] = f2bf(u1.y);
    tmp.u[6] = f2bf(u1.z); tmp.u[7] = f2bf(u1.w);
    *(us8*)(xb + (size_t)i * 8) = tmp.v;
}

// ---------------- pull aggregation: mean over neighbors ----------------
// 2 rows per half-wave (16 rows/block); first-2 edge indices of BOTH rows loaded
// immediately after the shared rowptr read -> 4 independent row-loads in flight
// (vs 2), one fewer serial hop. Rare deg>2 rows take the remainder loops.
__global__ __launch_bounds__(256) void k_gather_mean(const unsigned short* __restrict__ xsrc,
                                                     const int* __restrict__ rowptr,
                                                     const int* __restrict__ eidx,
                                                     unsigned short* __restrict__ mean, int M) {
    int hw = threadIdx.x >> 5;            // half-wave 0..7
    int g = threadIdx.x & 31;
    int r0 = blockIdx.x * 16 + hw * 2;
    if (r0 >= M) return;
    int r1 = r0 + 1;
    int s0 = rowptr[r0];
    int s1 = rowptr[r0 + 1];
    int s2 = (r1 < M) ? rowptr[r1 + 1] : s1;
    int n0 = s1 - s0, n1 = s2 - s1;

    // batch the first-2 indices of both rows (covers the common deg<=2 case)
    int iA0 = (n0 > 0) ? eidx[s0] : 0;
    int iA1 = (n0 > 1) ? eidx[s0 + 1] : 0;
    int iB0 = (n1 > 0) ? eidx[s1] : 0;
    int iB1 = (n1 > 1) ? eidx[s1 + 1] : 0;

    float a0[8], a1[8];
#pragma unroll
    for (int j = 0; j < 8; ++j) { a0[j] = 0.f; a1[j] = 0.f; }

    union { us8 v; unsigned short u[8]; } vA0, vA1, vB0, vB1;
    if (n0 > 0) vA0.v = *(const us8*)(xsrc + (size_t)iA0 * 256 + g * 8);
    if (n0 > 1) vA1.v = *(const us8*)(xsrc + (size_t)iA1 * 256 + g * 8);
    if (n1 > 0) vB0.v = *(const us8*)(xsrc + (size_t)iB0 * 256 + g * 8);
    if (n1 > 1) vB1.v = *(const us8*)(xsrc + (size_t)iB1 * 256 + g * 8);
    if (n0 > 0) {
#pragma unroll
        for (int j = 0; j < 8; ++j) a0[j] += bf2f(vA0.u[j]);
    }
    if (n0 > 1) {
#pragma unroll
        for (int j = 0; j < 8; ++j) a0[j] += bf2f(vA1.u[j]);
    }
    if (n1 > 0) {
#pragma unroll
        for (int j = 0; j < 8; ++j) a1[j] += bf2f(vB0.u[j]);
    }
    if (n1 > 1) {
#pragma unroll
        for (int j = 0; j < 8; ++j) a1[j] += bf2f(vB1.u[j]);
    }
    // remainder (rare: deg > 2)
    for (int k = 2; k < n0; ++k) {
        int s = eidx[s0 + k];
        union { us8 v; unsigned short u[8]; } vv;
        vv.v = *(const us8*)(xsrc + (size_t)s * 256 + g * 8);
#pragma unroll
        for (int j = 0; j < 8; ++j) a0[j] += bf2f(vv.u[j]);
    }
    for (int k = 2; k < n1; ++k) {
        int s = eidx[s1 + k];
        union { us8 v; unsigned short u[8]; } vv;
        vv.v = *(const us8*)(xsrc + (size_t)s * 256 + g * 8);
#pragma unroll
        for (int j = 0; j < 8; ++j) a1[j] += bf2f(vv.u[j]);
    }

    float ri0 = (n0 > 0) ? 1.0f / (float)n0 : 0.0f;
    union { us8 v; unsigned short u[8]; } o0;
#pragma unroll
    for (int j = 0; j < 8; ++j) o0.u[j] = f2bf(a0[j] * ri0);
    *(us8*)(mean + (size_t)r0 * 256 + g * 8) = o0.v;
    if (r1 < M) {
        float ri1 = (n1 > 0) ? 1.0f / (float)n1 : 0.0f;
        union { us8 v; unsigned short u[8]; } o1;
#pragma unroll
        for (int j = 0; j < 8; ++j) o1.u[j] = f2bf(a1[j] * ri1);
        *(us8*)(mean + (size_t)r1 * 256 + g * 8) = o1.v;
    }
}

// ---------------- weight conversion into K-tiled fragment order ----------------
__global__ __launch_bounds__(256) void k_convw(const float* __restrict__ Wl,
                                               const float* __restrict__ Wr,
                                               const float* __restrict__ fcW,
                                               unsigned short* __restrict__ Wc1,
                                               unsigned short* __restrict__ Wc2,
                                               unsigned short* __restrict__ fcWb) {
    int idx = blockIdx.x * 256 + threadIdx.x;
    if (idx < 262144) {
        int layer = idx >> 17;
        int i = idx & 131071;
        int kt = i >> 14;
        int sub = (i >> 10) & 15;
        int kk = (i >> 9) & 1;
        int sl = (i >> 3) & 63;
        int e = i & 7;
        int n = sub * 16 + (sl & 15);
        int k = kt * 64 + kk * 32 + (sl >> 4) * 8 + e;
        int base = layer * 196608;
        float v = (k < 256) ? Wl[base + n * 256 + k] : Wr[base + n * 256 + (k - 256)];
        (layer ? Wc2 : Wc1)[i] = f2bf(v);
    } else {
        int i = idx - 262144;
        if (i < 32768) {
            int kt = i >> 13;
            int sub = (i >> 10) & 7;
            int kk = (i >> 9) & 1;
            int sl = (i >> 3) & 63;
            int e = i & 7;
            int n = sub * 16 + (sl & 15);
            int k = kt * 64 + kk * 32 + (sl >> 4) * 8 + e;
            fcWb[i] = f2bf(fcW[n * 256 + k]);
        }
    }
}

// ---------------- layer-1 GEMM: h = relu([mean | xs] @ Wc^T + bias) ----------------
// R12 best-known structure: (256,3); A->tri-buf LDS; B->regs, bottom-of-iter prefetch.
__global__ __launch_bounds__(256, 3) void k_sage_gemm(const unsigned short* __restrict__ meanb,
                                                      const unsigned short* __restrict__ xs,
                                                      const unsigned short* __restrict__ Wct,
                                                      const float* __restrict__ bias,
                                                      unsigned short* __restrict__ out, int M) {
    __shared__ __align__(16) unsigned short Asm[3][4096];   // 64 rows x 64 k, frag-major
    const int t = threadIdx.x;
    const int w = t >> 6, l = t & 63;
    const int lrow = l & 15, slot = l >> 4;
    const int row0 = blockIdx.x * 64;

    int a_row = row0 + w * 16 + lrow;
    if (a_row > M - 1) a_row = M - 1;
    const size_t a_base = (size_t)a_row * 256 + slot * 8;

    f32x4 acc[4][4];
#pragma unroll
    for (int n = 0; n < 4; ++n)
#pragma unroll
        for (int m = 0; m < 4; ++m)
#pragma unroll
            for (int j = 0; j < 4; ++j) acc[n][m][j] = 0.0f;

    auto stageA = [&](int bb, int kt) {
        const unsigned short* src = (kt < 4) ? meanb + a_base + kt * 64
                                             : xs + a_base + (kt - 4) * 64;
        gload16(src,      &Asm[bb][w * 1024]);
        gload16(src + 32, &Asm[bb][w * 1024 + 512]);
    };
    bf16x8 bfr[4][2];
    auto loadB = [&](int kt) {
#pragma unroll
        for (int m = 0; m < 4; ++m)
#pragma unroll
            for (int kk = 0; kk < 2; ++kk)
                bfr[m][kk] = *(const bf16x8*)(Wct + (size_t)kt * 16384
                                              + (size_t)(w * 4 + m) * 1024 + kk * 512 + l * 8);
    };

    stageA(0, 0);
    stageA(1, 1);
    loadB(0);

    bf16x8 af[4];
#pragma unroll
    for (int kt = 0; kt < 8; ++kt) {
        const int cb = kt % 3;
        if (kt < 7) { asm volatile("s_waitcnt vmcnt(10)" ::: "memory"); }
        else        { asm volatile("s_waitcnt vmcnt(8)"  ::: "memory"); }
        __builtin_amdgcn_s_barrier();
        __builtin_amdgcn_sched_barrier(0);
        if (kt < 6) stageA((kt + 2) % 3, kt + 2);
#pragma unroll
        for (int kk = 0; kk < 2; ++kk) {
#pragma unroll
            for (int n = 0; n < 4; ++n)
                af[n] = *(const bf16x8*)(&Asm[cb][n * 1024 + kk * 512 + l * 8]);
            __builtin_amdgcn_s_setprio(1);
#pragma unroll
            for (int n = 0; n < 4; ++n)
#pragma unroll
                for (int m = 0; m < 4; ++m)
                    acc[n][m] = __builtin_amdgcn_mfma_f32_16x16x32_bf16(bfr[m][kk], af[n], acc[n][m], 0, 0, 0);
            __builtin_amdgcn_s_setprio(0);
        }
        __builtin_amdgcn_sched_barrier(0);
        if (kt < 7) loadB(kt + 1);   // bottom-of-iter B prefetch (bfr regs now free)
        asm volatile("s_waitcnt lgkmcnt(0)" ::: "memory");
    }

#pragma unroll
    for (int n = 0; n < 4; ++n) {
        const int grow = row0 + n * 16 + lrow;
        if (grow >= M) continue;
#pragma unroll
        for (int m = 0; m < 4; ++m) {
            const int gcol = w * 64 + m * 16 + slot * 4;
            f32x4 bv = *(const f32x4*)(bias + gcol);
            us4 o;
            o.x = f2bf(fmaxf(acc[n][m][0] + bv.x, 0.f));
            o.y = f2bf(fmaxf(acc[n][m][1] + bv.y, 0.f));
            o.z = f2bf(fmaxf(acc[n][m][2] + bv.z, 0.f));
            o.w = f2bf(fmaxf(acc[n][m][3] + bv.w, 0.f));
            *(us4*)(out + (size_t)grow * 256 + gcol) = o;
        }
    }
}

// ---------------- FUSED layer-2 + fc: out = relu([mean|h]@Wc2^T + bl) @ fcW^T + fcb ----
__global__ __launch_bounds__(256, 3) void k_sage_fc_gemm(const unsigned short* __restrict__ meanb,
                                                         const unsigned short* __restrict__ xs,
                                                         const unsigned short* __restrict__ Wct,
                                                         const float* __restrict__ bias,
                                                         const unsigned short* __restrict__ fcWbt,
                                                         const float* __restrict__ fcb,
                                                         float* __restrict__ out, int M) {
    __shared__ __align__(16) unsigned short pool[16384];   // 32 KB; tri-buffer aliases first 24 KB
    unsigned short (*Asm)[4096] = (unsigned short(*)[4096])pool;
    const int t = threadIdx.x;
    const int w = t >> 6, l = t & 63;
    const int lrow = l & 15, slot = l >> 4;
    const int row0 = blockIdx.x * 64;

    int a_row = row0 + w * 16 + lrow;
    if (a_row > M - 1) a_row = M - 1;
    const size_t a_base = (size_t)a_row * 256 + slot * 8;

    f32x4 acc[4][4];
#pragma unroll
    for (int n = 0; n < 4; ++n)
#pragma unroll
        for (int m = 0; m < 4; ++m)
#pragma unroll
            for (int j = 0; j < 4; ++j) acc[n][m][j] = 0.0f;

    auto stageA = [&](int bb, int kt) {
        const unsigned short* src = (kt < 4) ? meanb + a_base + kt * 64
                                             : xs + a_base + (kt - 4) * 64;
        gload16(src,      &Asm[bb][w * 1024]);
        gload16(src + 32, &Asm[bb][w * 1024 + 512]);
    };
    bf16x8 bfr[4][2];
    auto loadB = [&](int kt) {
#pragma unroll
        for (int m = 0; m < 4; ++m)
#pragma unroll
            for (int kk = 0; kk < 2; ++kk)
                bfr[m][kk] = *(const bf16x8*)(Wct + (size_t)kt * 16384
                                              + (size_t)(w * 4 + m) * 1024 + kk * 512 + l * 8);
    };

    stageA(0, 0);
    stageA(1, 1);
    loadB(0);

    bf16x8 af[4];
#pragma unroll
    for (int kt = 0; kt < 8; ++kt) {
        const int cb = kt % 3;
        if (kt < 7) { asm volatile("s_waitcnt vmcnt(10)" ::: "memory"); }
        else        { asm volatile("s_waitcnt vmcnt(8)"  ::: "memory"); }
        __builtin_amdgcn_s_barrier();
        __builtin_amdgcn_sched_barrier(0);
        if (kt < 6) stageA((kt + 2) % 3, kt + 2);
#pragma unroll
        for (int kk = 0; kk < 2; ++kk) {
#pragma unroll
            for (int n = 0; n < 4; ++n)
                af[n] = *(const bf16x8*)(&Asm[cb][n * 1024 + kk * 512 + l * 8]);
            __builtin_amdgcn_s_setprio(1);
#pragma unroll
            for (int n = 0; n < 4; ++n)
#pragma unroll
                for (int m = 0; m < 4; ++m)
                    acc[n][m] = __builtin_amdgcn_mfma_f32_16x16x32_bf16(bfr[m][kk], af[n], acc[n][m], 0, 0, 0);
            __builtin_amdgcn_s_setprio(0);
        }
        __builtin_amdgcn_sched_barrier(0);
        if (kt < 7) loadB(kt + 1);   // bottom-of-iter B prefetch
        asm volatile("s_waitcnt lgkmcnt(0)" ::: "memory");
    }

    // g = relu(acc + bias) -> bf16 -> pool (frag-major, conflict-free)
    __syncthreads();
#pragma unroll
    for (int n = 0; n < 4; ++n) {
#pragma unroll
        for (int m = 0; m < 4; ++m) {
            const int gcol = w * 64 + m * 16 + slot * 4;
            f32x4 bv = *(const f32x4*)(bias + gcol);
            us4 o;
            o.x = f2bf(fmaxf(acc[n][m][0] + bv.x, 0.f));
            o.y = f2bf(fmaxf(acc[n][m][1] + bv.y, 0.f));
            o.z = f2bf(fmaxf(acc[n][m][2] + bv.z, 0.f));
            o.w = f2bf(fmaxf(acc[n][m][3] + bv.w, 0.f));
            int addr = w * 4096 + n * 1024 + (m >> 1) * 512
                     + ((((m & 1) * 2 + (slot >> 1)) * 16 + lrow) * 8) + (slot & 1) * 4;
            *(us4*)(&pool[addr]) = o;
        }
    }
    __syncthreads();

    // fc mini-GEMM: out[64x128] = g @ fcW^T + fcb
    f32x4 acc2[4][2];
#pragma unroll
    for (int n = 0; n < 4; ++n)
#pragma unroll
        for (int m = 0; m < 2; ++m)
#pragma unroll
            for (int j = 0; j < 4; ++j) acc2[n][m][j] = 0.0f;

#pragma unroll
    for (int kt2 = 0; kt2 < 4; ++kt2) {
        bf16x8 bw[2][2];
#pragma unroll
        for (int m = 0; m < 2; ++m)
#pragma unroll
            for (int kk = 0; kk < 2; ++kk)
                bw[m][kk] = *(const bf16x8*)(fcWbt + (size_t)kt2 * 8192
                                             + (size_t)(w * 2 + m) * 1024 + kk * 512 + l * 8);
#pragma unroll
        for (int kk = 0; kk < 2; ++kk) {
            bf16x8 ag[4];
#pragma unroll
            for (int n = 0; n < 4; ++n)
                ag[n] = *(const bf16x8*)(&pool[kt2 * 4096 + n * 1024 + kk * 512 + l * 8]);
#pragma unroll
            for (int n = 0; n < 4; ++n)
#pragma unroll
                for (int m = 0; m < 2; ++m)
                    acc2[n][m] = __builtin_amdgcn_mfma_f32_16x16x32_bf16(bw[m][kk], ag[n], acc2[n][m], 0, 0, 0);
        }
    }

#pragma unroll
    for (int n = 0; n < 4; ++n) {
        const int grow = row0 + n * 16 + lrow;
        if (grow >= M) continue;
#pragma unroll
        for (int m = 0; m < 2; ++m) {
            const int gcol = w * 32 + m * 16 + slot * 4;
            f32x4 bv = *(const f32x4*)(fcb + gcol);
            f32x4 o;
            o.x = acc2[n][m][0] + bv.x;
            o.y = acc2[n][m][1] + bv.y;
            o.z = acc2[n][m][2] + bv.z;
            o.w = acc2[n][m][3] + bv.w;
            *(f32x4*)(out + (size_t)grow * 128 + gcol) = o;
        }
    }
}

extern "C" void kernel_launch(void* const* d_in, const int* in_sizes, int n_in,
                              void* d_out, int out_size, void* d_ws, size_t ws_size,
                              hipStream_t stream) {
    const float* x_word = (const float*)d_in[0];
    const float* Wl  = (const float*)d_in[3];
    const float* bl  = (const float*)d_in[4];
    const float* Wr  = (const float*)d_in[5];
    const float* fcW = (const float*)d_in[6];
    const float* fcb = (const float*)d_in[7];
    const int* src = (const int*)d_in[8];
    const int* dst = (const int*)d_in[9];

    const int M = in_sizes[0] / 256;   // 200000
    const int E = in_sizes[8];         // 400000
    const int NB = (M + 1023) / 1024;

    char* ws = (char*)d_ws;
    size_t off = 0;
    auto alloc = [&](size_t bytes) {
        void* p = ws + off;
        off = (off + bytes + 255) & ~(size_t)255;
        return p;
    };
    int* cnt_i  = (int*)alloc((size_t)M * 4);
    int* rowptr = (int*)alloc((size_t)(M + 1) * 4);
    int* cursor = (int*)alloc((size_t)M * 4);
    int* eidx   = (int*)alloc((size_t)E * 4);
    int* bsum   = (int*)alloc((size_t)NB * 4);
    unsigned short* xb    = (unsigned short*)alloc((size_t)M * 256 * 2);
    unsigned short* meanb = (unsigned short*)alloc((size_t)M * 256 * 2);
    unsigned short* h     = (unsigned short*)alloc((size_t)M * 256 * 2);
    unsigned short* Wc1   = (unsigned short*)alloc(131072 * 2);
    unsigned short* Wc2   = (unsigned short*)alloc(131072 * 2);
    unsigned short* fcWb  = (unsigned short*)alloc(32768 * 2);

    // CSR build
    k_zero<<<(M + 255) / 256, 256, 0, stream>>>(cnt_i, M);
    k_hist<<<(E + 255) / 256, 256, 0, stream>>>(dst, cnt_i, E);
    k_bsum<<<NB, 256, 0, stream>>>(cnt_i, bsum, M);
    k_scanb<<<1, 256, 0, stream>>>(bsum, NB, rowptr, M, E);
    k_rowptr<<<NB, 256, 0, stream>>>(cnt_i, bsum, rowptr, cursor, M);
    k_place<<<(E + 255) / 256, 256, 0, stream>>>(src, dst, cursor, eidx, E);

    // weights (tiled) + x -> bf16 (row-major)
    k_convw<<<1152, 256, 0, stream>>>(Wl, Wr, fcW, Wc1, Wc2, fcWb);
    k_convx<<<(M * 256 / 8 + 255) / 256, 256, 0, stream>>>(x_word, xb, M * 256 / 8);

    const int GB = (M + 63) / 64;

    // Layer 1
    k_gather_mean<<<(M + 15) / 16, 256, 0, stream>>>(xb, rowptr, eidx, meanb, M);
    k_sage_gemm<<<GB, 256, 0, stream>>>(meanb, xb, Wc1, bl, h, M);

    // Layer 2 + fc head, fused
    k_gather_mean<<<(M + 15) / 16, 256, 0, stream>>>(h, rowptr, eidx, meanb, M);
    k_sage_fc_gemm<<<GB, 256, 0, stream>>>(meanb, h, Wc2, bl + 3 * 256, fcWb, fcb,
                                           (float*)d_out, M);
}

// Round 15
// 426.684 us; speedup vs baseline: 2.4383x; 1.0408x over previous
//
#include <hip/hip_runtime.h>

typedef __attribute__((ext_vector_type(8))) short bf16x8;
typedef __attribute__((ext_vector_type(4))) float f32x4;
typedef __attribute__((ext_vector_type(4))) unsigned short us4;
typedef __attribute__((ext_vector_type(8))) unsigned short us8;

static __device__ __forceinline__ float bf2f(unsigned short u) {
    union { unsigned int i; float f; } cv; cv.i = ((unsigned int)u) << 16;
    return cv.f;
}
static __device__ __forceinline__ unsigned short f2bf(float f) {
    union { float f; unsigned int i; } cv; cv.f = f;
    unsigned int x = cv.i;
    unsigned int lsb = (x >> 16) & 1u;
    x += 0x7fffu + lsb;
    return (unsigned short)(x >> 16);
}

// async global->LDS, 16B per lane; LDS dest is wave-uniform base + lane*16
static __device__ __forceinline__ void gload16(const void* g, void* l) {
    __builtin_amdgcn_global_load_lds(
        (const __attribute__((address_space(1))) void*)g,
        (__attribute__((address_space(3))) void*)l, 16, 0, 0);
}

// ---------------- zero (hipMemsetAsync's runtime fill kernel writes 819MB) ----------------
__global__ __launch_bounds__(256) void k_zero(int* __restrict__ p, int n) {
    int i = blockIdx.x * 256 + threadIdx.x;
    if (i < n) p[i] = 0;
}

// ---------------- CSR build ----------------
__global__ __launch_bounds__(256) void k_hist(const int* __restrict__ dst,
                                              int* __restrict__ cnt, int E) {
    int i = blockIdx.x * 256 + threadIdx.x;
    if (i < E) atomicAdd(&cnt[dst[i]], 1);
}

__global__ __launch_bounds__(256) void k_bsum(const int* __restrict__ cnt,
                                              int* __restrict__ bsum, int M) {
    __shared__ int sm[256];
    int t = threadIdx.x;
    int base = blockIdx.x * 1024 + t * 4;
    int s = 0;
#pragma unroll
    for (int j = 0; j < 4; ++j) {
        int i = base + j;
        if (i < M) s += cnt[i];
    }
    sm[t] = s;
    __syncthreads();
    for (int off = 128; off; off >>= 1) {
        if (t < off) sm[t] += sm[t + off];
        __syncthreads();
    }
    if (t == 0) bsum[blockIdx.x] = sm[0];
}

// parallel exclusive scan of bsum (NB <= 256)
__global__ __launch_bounds__(256) void k_scanb(int* __restrict__ bsum, int NB,
                                               int* __restrict__ rowptr, int M, int E) {
    __shared__ int sm[256];
    int t = threadIdx.x;
    int v = (t < NB) ? bsum[t] : 0;
    sm[t] = v;
    __syncthreads();
    for (int off = 1; off < 256; off <<= 1) {
        int u = (t >= off) ? sm[t - off] : 0;
        __syncthreads();
        sm[t] += u;
        __syncthreads();
    }
    if (t < NB) bsum[t] = sm[t] - v;   // exclusive
    if (t == 0) rowptr[M] = E;
}

__global__ __launch_bounds__(256) void k_rowptr(const int* __restrict__ cnt,
                                                const int* __restrict__ bsum,
                                                int* __restrict__ rowptr,
                                                int* __restrict__ cursor, int M) {
    __shared__ int sm[256];
    int t = threadIdx.x;
    int base = blockIdx.x * 1024 + t * 4;
    int c[4];
    int ts = 0;
#pragma unroll
    for (int j = 0; j < 4; ++j) {
        int i = base + j;
        c[j] = (i < M) ? cnt[i] : 0;
        ts += c[j];
    }
    sm[t] = ts;
    __syncthreads();
    for (int off = 1; off < 256; off <<= 1) {
        int v = (t >= off) ? sm[t - off] : 0;
        __syncthreads();
        sm[t] += v;
        __syncthreads();
    }
    int ex = bsum[blockIdx.x] + sm[t] - ts;
#pragma unroll
    for (int j = 0; j < 4; ++j) {
        int i = base + j;
        if (i < M) {
            rowptr[i] = ex;
            cursor[i] = ex;
        }
        ex += c[j];
    }
}

__global__ __launch_bounds__(256) void k_place(const int* __restrict__ src,
                                               const int* __restrict__ dst,
                                               int* __restrict__ cursor,
                                               int* __restrict__ eidx, int E) {
    int i = blockIdx.x * 256 + threadIdx.x;
    if (i < E) {
        int slot = atomicAdd(&cursor[dst[i]], 1);
        eidx[slot] = src[i];
    }
}

// ---------------- f32 -> bf16 row-major convert ----------------
__global__ __launch_bounds__(256) void k_convx(const float* __restrict__ x,
                                               unsigned short* __restrict__ xb, int n8) {
    int i = blockIdx.x * 256 + threadIdx.x;
    if (i >= n8) return;
    const f32x4* p = (const f32x4*)(x + (size_t)i * 8);
    f32x4 u0 = p[0], u1 = p[1];
    union { us8 v; unsigned short u[8]; } tmp;
    tmp.u[0] = f2bf(u0.x); tmp.u[1] = f2bf(u0.y);
    tmp.u[2] = f2bf(u0.z); tmp.u[3] = f2bf(u0.w);
    tmp.u[4] = f2bf(u1.x); tmp.u[5] = f2bf(u1.y);
    tmp.u[6] = f2bf(u1.z); tmp.u[7] = f2bf(u1.w);
    *(us8*)(xb + (size_t)i * 8) = tmp.v;
}

// ---------------- pull aggregation: mean over neighbors (R12 best form) ----------------
// half-wave (32 lanes) per row, us8 16-B loads; 2-way edge unroll for MLP.
__global__ __launch_bounds__(256) void k_gather_mean(const unsigned short* __restrict__ xsrc,
                                                     const int* __restrict__ rowptr,
                                                     const int* __restrict__ eidx,
                                                     unsigned short* __restrict__ mean, int M) {
    int r = blockIdx.x * 8 + (threadIdx.x >> 5);
    if (r >= M) return;
    int g = threadIdx.x & 31;
    int s0 = rowptr[r], s1 = rowptr[r + 1];
    float a[8];
#pragma unroll
    for (int j = 0; j < 8; ++j) a[j] = 0.f;
    int e = s0;
    for (; e + 2 <= s1; e += 2) {
        int sA = eidx[e], sB = eidx[e + 1];
        union { us8 v; unsigned short u[8]; } vA, vB;
        vA.v = *(const us8*)(xsrc + (size_t)sA * 256 + g * 8);
        vB.v = *(const us8*)(xsrc + (size_t)sB * 256 + g * 8);
#pragma unroll
        for (int j = 0; j < 8; ++j) a[j] += bf2f(vA.u[j]) + bf2f(vB.u[j]);
    }
    if (e < s1) {
        int sA = eidx[e];
        union { us8 v; unsigned short u[8]; } vA;
        vA.v = *(const us8*)(xsrc + (size_t)sA * 256 + g * 8);
#pragma unroll
        for (int j = 0; j < 8; ++j) a[j] += bf2f(vA.u[j]);
    }
    float rinv = (s1 > s0) ? 1.0f / (float)(s1 - s0) : 0.0f;
    union { us8 v; unsigned short u[8]; } o;
#pragma unroll
    for (int j = 0; j < 8; ++j) o.u[j] = f2bf(a[j] * rinv);
    *(us8*)(mean + (size_t)r * 256 + g * 8) = o.v;
}

// ---------------- weight conversion into K-tiled fragment order ----------------
__global__ __launch_bounds__(256) void k_convw(const float* __restrict__ Wl,
                                               const float* __restrict__ Wr,
                                               const float* __restrict__ fcW,
                                               unsigned short* __restrict__ Wc1,
                                               unsigned short* __restrict__ Wc2,
                                               unsigned short* __restrict__ fcWb) {
    int idx = blockIdx.x * 256 + threadIdx.x;
    if (idx < 262144) {
        int layer = idx >> 17;
        int i = idx & 131071;
        int kt = i >> 14;
        int sub = (i >> 10) & 15;
        int kk = (i >> 9) & 1;
        int sl = (i >> 3) & 63;
        int e = i & 7;
        int n = sub * 16 + (sl & 15);
        int k = kt * 64 + kk * 32 + (sl >> 4) * 8 + e;
        int base = layer * 196608;
        float v = (k < 256) ? Wl[base + n * 256 + k] : Wr[base + n * 256 + (k - 256)];
        (layer ? Wc2 : Wc1)[i] = f2bf(v);
    } else {
        int i = idx - 262144;
        if (i < 32768) {
            int kt = i >> 13;
            int sub = (i >> 10) & 7;
            int kk = (i >> 9) & 1;
            int sl = (i >> 3) & 63;
            int e = i & 7;
            int n = sub * 16 + (sl & 15);
            int k = kt * 64 + kk * 32 + (sl >> 4) * 8 + e;
            fcWb[i] = f2bf(fcW[n * 256 + k]);
        }
    }
}

// ---------------- layer-1 GEMM: h = relu([mean | xs] @ Wc^T + bias) ----------------
// BK=128 variant of R12: 4 main iterations (half the barrier/wait overhead).
// A->tri-buf LDS (3x16KB, prefetch dist 2, vmcnt(20)); B->regs bfr[4][4],
// bottom-of-iter prefetch. (256,3): VGPR cap ~168, predicted use ~150.
__global__ __launch_bounds__(256, 3) void k_sage_gemm(const unsigned short* __restrict__ meanb,
                                                      const unsigned short* __restrict__ xs,
                                                      const unsigned short* __restrict__ Wct,
                                                      const float* __restrict__ bias,
                                                      unsigned short* __restrict__ out, int M) {
    __shared__ __align__(16) unsigned short Asm[3][8192];   // 64 rows x 128 k, frag-major
    const int t = threadIdx.x;
    const int w = t >> 6, l = t & 63;
    const int lrow = l & 15, slot = l >> 4;
    const int row0 = blockIdx.x * 64;

    int a_row = row0 + w * 16 + lrow;
    if (a_row > M - 1) a_row = M - 1;
    const size_t a_base = (size_t)a_row * 256 + slot * 8;

    f32x4 acc[4][4];
#pragma unroll
    for (int n = 0; n < 4; ++n)
#pragma unroll
        for (int m = 0; m < 4; ++m)
#pragma unroll
            for (int j = 0; j < 4; ++j) acc[n][m][j] = 0.0f;

    auto stageA = [&](int bb, int kt2) {
        const unsigned short* src = (kt2 < 2) ? meanb + a_base + kt2 * 128
                                              : xs + a_base + (kt2 - 2) * 128;
#pragma unroll
        for (int j = 0; j < 4; ++j)
            gload16(src + j * 32, &Asm[bb][w * 2048 + j * 512]);
    };
    bf16x8 bfr[4][4];
    auto loadB = [&](int kt2) {
#pragma unroll
        for (int m = 0; m < 4; ++m)
#pragma unroll
            for (int kk = 0; kk < 4; ++kk)
                bfr[m][kk] = *(const bf16x8*)(Wct + (size_t)(2 * kt2 + (kk >> 1)) * 16384
                                              + (size_t)(w * 4 + m) * 1024 + (kk & 1) * 512 + l * 8);
    };

    stageA(0, 0);
    stageA(1, 1);
    loadB(0);

    bf16x8 af[4];
#pragma unroll
    for (int kt2 = 0; kt2 < 4; ++kt2) {
        const int cb = kt2 % 3;
        // outstanding at top: A(kt2) 4 + A(kt2+1) 4 + B(kt2) 16 = 24 -> drain A(kt2)
        if (kt2 < 3) { asm volatile("s_waitcnt vmcnt(20)" ::: "memory"); }
        else         { asm volatile("s_waitcnt vmcnt(16)" ::: "memory"); }
        __builtin_amdgcn_s_barrier();
        __builtin_amdgcn_sched_barrier(0);
        if (kt2 < 2) stageA((kt2 + 2) % 3, kt2 + 2);
#pragma unroll
        for (int kk = 0; kk < 4; ++kk) {
#pragma unroll
            for (int n = 0; n < 4; ++n)
                af[n] = *(const bf16x8*)(&Asm[cb][n * 2048 + kk * 512 + l * 8]);
            __builtin_amdgcn_s_setprio(1);
#pragma unroll
            for (int n = 0; n < 4; ++n)
#pragma unroll
                for (int m = 0; m < 4; ++m)
                    acc[n][m] = __builtin_amdgcn_mfma_f32_16x16x32_bf16(bfr[m][kk], af[n], acc[n][m], 0, 0, 0);
            __builtin_amdgcn_s_setprio(0);
        }
        __builtin_amdgcn_sched_barrier(0);
        if (kt2 < 3) loadB(kt2 + 1);   // bottom-of-iter B prefetch (bfr regs now free)
        asm volatile("s_waitcnt lgkmcnt(0)" ::: "memory");
    }

#pragma unroll
    for (int n = 0; n < 4; ++n) {
        const int grow = row0 + n * 16 + lrow;
        if (grow >= M) continue;
#pragma unroll
        for (int m = 0; m < 4; ++m) {
            const int gcol = w * 64 + m * 16 + slot * 4;
            f32x4 bv = *(const f32x4*)(bias + gcol);
            us4 o;
            o.x = f2bf(fmaxf(acc[n][m][0] + bv.x, 0.f));
            o.y = f2bf(fmaxf(acc[n][m][1] + bv.y, 0.f));
            o.z = f2bf(fmaxf(acc[n][m][2] + bv.z, 0.f));
            o.w = f2bf(fmaxf(acc[n][m][3] + bv.w, 0.f));
            *(us4*)(out + (size_t)grow * 256 + gcol) = o;
        }
    }
}

// ---------------- FUSED layer-2 + fc: out = relu([mean|h]@Wc2^T + bl) @ fcW^T + fcb ----
// Same BK=128 main loop; g tile -> LDS pool (aliases tri-buffer) -> fc mini-GEMM.
__global__ __launch_bounds__(256, 3) void k_sage_fc_gemm(const unsigned short* __restrict__ meanb,
                                                         const unsigned short* __restrict__ xs,
                                                         const unsigned short* __restrict__ Wct,
                                                         const float* __restrict__ bias,
                                                         const unsigned short* __restrict__ fcWbt,
                                                         const float* __restrict__ fcb,
                                                         float* __restrict__ out, int M) {
    __shared__ __align__(16) unsigned short pool[24576];   // 48 KB tri-buffer; g-tile aliases first 32 KB
    unsigned short (*Asm)[8192] = (unsigned short(*)[8192])pool;
    const int t = threadIdx.x;
    const int w = t >> 6, l = t & 63;
    const int lrow = l & 15, slot = l >> 4;
    const int row0 = blockIdx.x * 64;

    int a_row = row0 + w * 16 + lrow;
    if (a_row > M - 1) a_row = M - 1;
    const size_t a_base = (size_t)a_row * 256 + slot * 8;

    f32x4 acc[4][4];
#pragma unroll
    for (int n = 0; n < 4; ++n)
#pragma unroll
        for (int m = 0; m < 4; ++m)
#pragma unroll
            for (int j = 0; j < 4; ++j) acc[n][m][j] = 0.0f;

    auto stageA = [&](int bb, int kt2) {
        const unsigned short* src = (kt2 < 2) ? meanb + a_base + kt2 * 128
                                              : xs + a_base + (kt2 - 2) * 128;
#pragma unroll
        for (int j = 0; j < 4; ++j)
            gload16(src + j * 32, &Asm[bb][w * 2048 + j * 512]);
    };
    bf16x8 bfr[4][4];
    auto loadB = [&](int kt2) {
#pragma unroll
        for (int m = 0; m < 4; ++m)
#pragma unroll
            for (int kk = 0; kk < 4; ++kk)
                bfr[m][kk] = *(const bf16x8*)(Wct + (size_t)(2 * kt2 + (kk >> 1)) * 16384
                                              + (size_t)(w * 4 + m) * 1024 + (kk & 1) * 512 + l * 8);
    };

    stageA(0, 0);
    stageA(1, 1);
    loadB(0);

    bf16x8 af[4];
#pragma unroll
    for (int kt2 = 0; kt2 < 4; ++kt2) {
        const int cb = kt2 % 3;
        if (kt2 < 3) { asm volatile("s_waitcnt vmcnt(20)" ::: "memory"); }
        else         { asm volatile("s_waitcnt vmcnt(16)" ::: "memory"); }
        __builtin_amdgcn_s_barrier();
        __builtin_amdgcn_sched_barrier(0);
        if (kt2 < 2) stageA((kt2 + 2) % 3, kt2 + 2);
#pragma unroll
        for (int kk = 0; kk < 4; ++kk) {
#pragma unroll
            for (int n = 0; n < 4; ++n)
                af[n] = *(const bf16x8*)(&Asm[cb][n * 2048 + kk * 512 + l * 8]);
            __builtin_amdgcn_s_setprio(1);
#pragma unroll
            for (int n = 0; n < 4; ++n)
#pragma unroll
                for (int m = 0; m < 4; ++m)
                    acc[n][m] = __builtin_amdgcn_mfma_f32_16x16x32_bf16(bfr[m][kk], af[n], acc[n][m], 0, 0, 0);
            __builtin_amdgcn_s_setprio(0);
        }
        __builtin_amdgcn_sched_barrier(0);
        if (kt2 < 3) loadB(kt2 + 1);
        asm volatile("s_waitcnt lgkmcnt(0)" ::: "memory");
    }

    // g = relu(acc + bias) -> bf16 -> pool (frag-major, conflict-free)
    __syncthreads();
#pragma unroll
    for (int n = 0; n < 4; ++n) {
#pragma unroll
        for (int m = 0; m < 4; ++m) {
            const int gcol = w * 64 + m * 16 + slot * 4;
            f32x4 bv = *(const f32x4*)(bias + gcol);
            us4 o;
            o.x = f2bf(fmaxf(acc[n][m][0] + bv.x, 0.f));
            o.y = f2bf(fmaxf(acc[n][m][1] + bv.y, 0.f));
            o.z = f2bf(fmaxf(acc[n][m][2] + bv.z, 0.f));
            o.w = f2bf(fmaxf(acc[n][m][3] + bv.w, 0.f));
            int addr = w * 4096 + n * 1024 + (m >> 1) * 512
                     + ((((m & 1) * 2 + (slot >> 1)) * 16 + lrow) * 8) + (slot & 1) * 4;
            *(us4*)(&pool[addr]) = o;
        }
    }
    __syncthreads();

    // fc mini-GEMM: out[64x128] = g @ fcW^T + fcb (unchanged: 4 col-tiles of 64 k)
    f32x4 acc2[4][2];
#pragma unroll
    for (int n = 0; n < 4; ++n)
#pragma unroll
        for (int m = 0; m < 2; ++m)
#pragma unroll
            for (int j = 0; j < 4; ++j) acc2[n][m][j] = 0.0f;

#pragma unroll
    for (int kt2 = 0; kt2 < 4; ++kt2) {
        bf16x8 bw[2][2];
#pragma unroll
        for (int m = 0; m < 2; ++m)
#pragma unroll
            for (int kk = 0; kk < 2; ++kk)
                bw[m][kk] = *(const bf16x8*)(fcWbt + (size_t)kt2 * 8192
                                             + (size_t)(w * 2 + m) * 1024 + kk * 512 + l * 8);
#pragma unroll
        for (int kk = 0; kk < 2; ++kk) {
            bf16x8 ag[4];
#pragma unroll
            for (int n = 0; n < 4; ++n)
                ag[n] = *(const bf16x8*)(&pool[kt2 * 4096 + n * 1024 + kk * 512 + l * 8]);
#pragma unroll
            for (int n = 0; n < 4; ++n)
#pragma unroll
                for (int m = 0; m < 2; ++m)
                    acc2[n][m] = __builtin_amdgcn_mfma_f32_16x16x32_bf16(bw[m][kk], ag[n], acc2[n][m], 0, 0, 0);
        }
    }

#pragma unroll
    for (int n = 0; n < 4; ++n) {
        const int grow = row0 + n * 16 + lrow;
        if (grow >= M) continue;
#pragma unroll
        for (int m = 0; m < 2; ++m) {
            const int gcol = w * 32 + m * 16 + slot * 4;
            f32x4 bv = *(const f32x4*)(fcb + gcol);
            f32x4 o;
            o.x = acc2[n][m][0] + bv.x;
            o.y = acc2[n][m][1] + bv.y;
            o.z = acc2[n][m][2] + bv.z;
            o.w = acc2[n][m][3] + bv.w;
            *(f32x4*)(out + (size_t)grow * 128 + gcol) = o;
        }
    }
}

extern "C" void kernel_launch(void* const* d_in, const int* in_sizes, int n_in,
                              void* d_out, int out_size, void* d_ws, size_t ws_size,
                              hipStream_t stream) {
    const float* x_word = (const float*)d_in[0];
    const float* Wl  = (const float*)d_in[3];
    const float* bl  = (const float*)d_in[4];
    const float* Wr  = (const float*)d_in[5];
    const float* fcW = (const float*)d_in[6];
    const float* fcb = (const float*)d_in[7];
    const int* src = (const int*)d_in[8];
    const int* dst = (const int*)d_in[9];

    const int M = in_sizes[0] / 256;   // 200000
    const int E = in_sizes[8];         // 400000
    const int NB = (M + 1023) / 1024;

    char* ws = (char*)d_ws;
    size_t off = 0;
    auto alloc = [&](size_t bytes) {
        void* p = ws + off;
        off = (off + bytes + 255) & ~(size_t)255;
        return p;
    };
    int* cnt_i  = (int*)alloc((size_t)M * 4);
    int* rowptr = (int*)alloc((size_t)(M + 1) * 4);
    int* cursor = (int*)alloc((size_t)M * 4);
    int* eidx   = (int*)alloc((size_t)E * 4);
    int* bsum   = (int*)alloc((size_t)NB * 4);
    unsigned short* xb    = (unsigned short*)alloc((size_t)M * 256 * 2);
    unsigned short* meanb = (unsigned short*)alloc((size_t)M * 256 * 2);
    unsigned short* h     = (unsigned short*)alloc((size_t)M * 256 * 2);
    unsigned short* Wc1   = (unsigned short*)alloc(131072 * 2);
    unsigned short* Wc2   = (unsigned short*)alloc(131072 * 2);
    unsigned short* fcWb  = (unsigned short*)alloc(32768 * 2);

    // CSR build
    k_zero<<<(M + 255) / 256, 256, 0, stream>>>(cnt_i, M);
    k_hist<<<(E + 255) / 256, 256, 0, stream>>>(dst, cnt_i, E);
    k_bsum<<<NB, 256, 0, stream>>>(cnt_i, bsum, M);
    k_scanb<<<1, 256, 0, stream>>>(bsum, NB, rowptr, M, E);
    k_rowptr<<<NB, 256, 0, stream>>>(cnt_i, bsum, rowptr, cursor, M);
    k_place<<<(E + 255) / 256, 256, 0, stream>>>(src, dst, cursor, eidx, E);

    // weights (tiled) + x -> bf16 (row-major)
    k_convw<<<1152, 256, 0, stream>>>(Wl, Wr, fcW, Wc1, Wc2, fcWb);
    k_convx<<<(M * 256 / 8 + 255) / 256, 256, 0, stream>>>(x_word, xb, M * 256 / 8);

    const int GB = (M + 63) / 64;

    // Layer 1
    k_gather_mean<<<(M + 7) / 8, 256, 0, stream>>>(xb, rowptr, eidx, meanb, M);
    k_sage_gemm<<<GB, 256, 0, stream>>>(meanb, xb, Wc1, bl, h, M);

    // Layer 2 + fc head, fused
    k_gather_mean<<<(M + 7) / 8, 256, 0, stream>>>(h, rowptr, eidx, meanb, M);
    k_sage_fc_gemm<<<GB, 256, 0, stream>>>(meanb, h, Wc2, bl + 3 * 256, fcWb, fcb,
                                           (float*)d_out, M);
}

// Round 16
// 418.272 us; speedup vs baseline: 2.4874x; 1.0201x over previous
//
#include <hip/hip_runtime.h>

typedef __attribute__((ext_vector_type(8))) short bf16x8;
typedef __attribute__((ext_vector_type(4))) float f32x4;
typedef __attribute__((ext_vector_type(4))) unsigned short us4;
typedef __attribute__((ext_vector_type(8))) unsigned short us8;

static __device__ __forceinline__ float bf2f(unsigned short u) {
    union { unsigned int i; float f; } cv; cv.i = ((unsigned int)u) << 16;
    return cv.f;
}
static __device__ __forceinline__ unsigned short f2bf(float f) {
    union { float f; unsigned int i; } cv; cv.f = f;
    unsigned int x = cv.i;
    unsigned int lsb = (x >> 16) & 1u;
    x += 0x7fffu + lsb;
    return (unsigned short)(x >> 16);
}

// async global->LDS, 16B per lane; LDS dest is wave-uniform base + lane*16
static __device__ __forceinline__ void gload16(const void* g, void* l) {
    __builtin_amdgcn_global_load_lds(
        (const __attribute__((address_space(1))) void*)g,
        (__attribute__((address_space(3))) void*)l, 16, 0, 0);
}

// ---------------- fused prep: convx (f32->bf16) + convw (weights->tiled bf16) + zero cnt ----
// Independent work items packed into one launch so they overlap instead of serializing.
// Block-range partition -> no intra-block divergence.
__global__ __launch_bounds__(256) void k_prep(const float* __restrict__ x,
                                              unsigned short* __restrict__ xb, int n8, int nbx,
                                              const float* __restrict__ Wl,
                                              const float* __restrict__ Wr,
                                              const float* __restrict__ fcW,
                                              unsigned short* __restrict__ Wc1,
                                              unsigned short* __restrict__ Wc2,
                                              unsigned short* __restrict__ fcWb,
                                              int* __restrict__ cnt, int M) {
    int b = blockIdx.x;
    int t = threadIdx.x;
    if (b < nbx) {
        // convx
        int i = b * 256 + t;
        if (i >= n8) return;
        const f32x4* p = (const f32x4*)(x + (size_t)i * 8);
        f32x4 u0 = p[0], u1 = p[1];
        union { us8 v; unsigned short u[8]; } tmp;
        tmp.u[0] = f2bf(u0.x); tmp.u[1] = f2bf(u0.y);
        tmp.u[2] = f2bf(u0.z); tmp.u[3] = f2bf(u0.w);
        tmp.u[4] = f2bf(u1.x); tmp.u[5] = f2bf(u1.y);
        tmp.u[6] = f2bf(u1.z); tmp.u[7] = f2bf(u1.w);
        *(us8*)(xb + (size_t)i * 8) = tmp.v;
    } else if (b < nbx + 1152) {
        // convw into K-tiled fragment order
        int idx = (b - nbx) * 256 + t;
        if (idx < 262144) {
            int layer = idx >> 17;
            int i = idx & 131071;
            int kt = i >> 14;
            int sub = (i >> 10) & 15;
            int kk = (i >> 9) & 1;
            int sl = (i >> 3) & 63;
            int e = i & 7;
            int n = sub * 16 + (sl & 15);
            int k = kt * 64 + kk * 32 + (sl >> 4) * 8 + e;
            int base = layer * 196608;
            float v = (k < 256) ? Wl[base + n * 256 + k] : Wr[base + n * 256 + (k - 256)];
            (layer ? Wc2 : Wc1)[i] = f2bf(v);
        } else {
            int i = idx - 262144;
            if (i < 32768) {
                int kt = i >> 13;
                int sub = (i >> 10) & 7;
                int kk = (i >> 9) & 1;
                int sl = (i >> 3) & 63;
                int e = i & 7;
                int n = sub * 16 + (sl & 15);
                int k = kt * 64 + kk * 32 + (sl >> 4) * 8 + e;
                fcWb[i] = f2bf(fcW[n * 256 + k]);
            }
        }
    } else {
        // zero cnt (replaces hipMemsetAsync: runtime fill kernel writes 819MB)
        int i = (b - nbx - 1152) * 256 + t;
        if (i < M) cnt[i] = 0;
    }
}

// ---------------- CSR build ----------------
__global__ __launch_bounds__(256) void k_hist(const int* __restrict__ dst,
                                              int* __restrict__ cnt, int E) {
    int i = blockIdx.x * 256 + threadIdx.x;
    if (i < E) atomicAdd(&cnt[dst[i]], 1);
}

__global__ __launch_bounds__(256) void k_bsum(const int* __restrict__ cnt,
                                              int* __restrict__ bsum, int M) {
    __shared__ int sm[256];
    int t = threadIdx.x;
    int base = blockIdx.x * 1024 + t * 4;
    int s = 0;
#pragma unroll
    for (int j = 0; j < 4; ++j) {
        int i = base + j;
        if (i < M) s += cnt[i];
    }
    sm[t] = s;
    __syncthreads();
    for (int off = 128; off; off >>= 1) {
        if (t < off) sm[t] += sm[t + off];
        __syncthreads();
    }
    if (t == 0) bsum[blockIdx.x] = sm[0];
}

// parallel exclusive scan of bsum (NB <= 256)
__global__ __launch_bounds__(256) void k_scanb(int* __restrict__ bsum, int NB,
                                               int* __restrict__ rowptr, int M, int E) {
    __shared__ int sm[256];
    int t = threadIdx.x;
    int v = (t < NB) ? bsum[t] : 0;
    sm[t] = v;
    __syncthreads();
    for (int off = 1; off < 256; off <<= 1) {
        int u = (t >= off) ? sm[t - off] : 0;
        __syncthreads();
        sm[t] += u;
        __syncthreads();
    }
    if (t < NB) bsum[t] = sm[t] - v;   // exclusive
    if (t == 0) rowptr[M] = E;
}

__global__ __launch_bounds__(256) void k_rowptr(const int* __restrict__ cnt,
                                                const int* __restrict__ bsum,
                                                int* __restrict__ rowptr,
                                                int* __restrict__ cursor, int M) {
    __shared__ int sm[256];
    int t = threadIdx.x;
    int base = blockIdx.x * 1024 + t * 4;
    int c[4];
    int ts = 0;
#pragma unroll
    for (int j = 0; j < 4; ++j) {
        int i = base + j;
        c[j] = (i < M) ? cnt[i] : 0;
        ts += c[j];
    }
    sm[t] = ts;
    __syncthreads();
    for (int off = 1; off < 256; off <<= 1) {
        int v = (t >= off) ? sm[t - off] : 0;
        __syncthreads();
        sm[t] += v;
        __syncthreads();
    }
    int ex = bsum[blockIdx.x] + sm[t] - ts;
#pragma unroll
    for (int j = 0; j < 4; ++j) {
        int i = base + j;
        if (i < M) {
            rowptr[i] = ex;
            cursor[i] = ex;
        }
        ex += c[j];
    }
}

__global__ __launch_bounds__(256) void k_place(const int* __restrict__ src,
                                               const int* __restrict__ dst,
                                               int* __restrict__ cursor,
                                               int* __restrict__ eidx, int E) {
    int i = blockIdx.x * 256 + threadIdx.x;
    if (i < E) {
        int slot = atomicAdd(&cursor[dst[i]], 1);
        eidx[slot] = src[i];
    }
}

// ---------------- pull aggregation: mean over neighbors (R12 best form) ----------------
// half-wave (32 lanes) per row, us8 16-B loads; 2-way edge unroll for MLP.
__global__ __launch_bounds__(256) void k_gather_mean(const unsigned short* __restrict__ xsrc,
                                                     const int* __restrict__ rowptr,
                                                     const int* __restrict__ eidx,
                                                     unsigned short* __restrict__ mean, int M) {
    int r = blockIdx.x * 8 + (threadIdx.x >> 5);
    if (r >= M) return;
    int g = threadIdx.x & 31;
    int s0 = rowptr[r], s1 = rowptr[r + 1];
    float a[8];
#pragma unroll
    for (int j = 0; j < 8; ++j) a[j] = 0.f;
    int e = s0;
    for (; e + 2 <= s1; e += 2) {
        int sA = eidx[e], sB = eidx[e + 1];
        union { us8 v; unsigned short u[8]; } vA, vB;
        vA.v = *(const us8*)(xsrc + (size_t)sA * 256 + g * 8);
        vB.v = *(const us8*)(xsrc + (size_t)sB * 256 + g * 8);
#pragma unroll
        for (int j = 0; j < 8; ++j) a[j] += bf2f(vA.u[j]) + bf2f(vB.u[j]);
    }
    if (e < s1) {
        int sA = eidx[e];
        union { us8 v; unsigned short u[8]; } vA;
        vA.v = *(const us8*)(xsrc + (size_t)sA * 256 + g * 8);
#pragma unroll
        for (int j = 0; j < 8; ++j) a[j] += bf2f(vA.u[j]);
    }
    float rinv = (s1 > s0) ? 1.0f / (float)(s1 - s0) : 0.0f;
    union { us8 v; unsigned short u[8]; } o;
#pragma unroll
    for (int j = 0; j < 8; ++j) o.u[j] = f2bf(a[j] * rinv);
    *(us8*)(mean + (size_t)r * 256 + g * 8) = o.v;
}

// ---------------- layer-1 GEMM: h = relu([mean | xs] @ Wc^T + bias) ----------------
// R15 best: BK=128, 4 main iterations; A->tri-buf LDS (3x16KB, dist-2, vmcnt(20));
// B->regs bfr[4][4], bottom-of-iter prefetch. (256,3).
__global__ __launch_bounds__(256, 3) void k_sage_gemm(const unsigned short* __restrict__ meanb,
                                                      const unsigned short* __restrict__ xs,
                                                      const unsigned short* __restrict__ Wct,
                                                      const float* __restrict__ bias,
                                                      unsigned short* __restrict__ out, int M) {
    __shared__ __align__(16) unsigned short Asm[3][8192];   // 64 rows x 128 k, frag-major
    const int t = threadIdx.x;
    const int w = t >> 6, l = t & 63;
    const int lrow = l & 15, slot = l >> 4;
    const int row0 = blockIdx.x * 64;

    int a_row = row0 + w * 16 + lrow;
    if (a_row > M - 1) a_row = M - 1;
    const size_t a_base = (size_t)a_row * 256 + slot * 8;

    f32x4 acc[4][4];
#pragma unroll
    for (int n = 0; n < 4; ++n)
#pragma unroll
        for (int m = 0; m < 4; ++m)
#pragma unroll
            for (int j = 0; j < 4; ++j) acc[n][m][j] = 0.0f;

    auto stageA = [&](int bb, int kt2) {
        const unsigned short* src = (kt2 < 2) ? meanb + a_base + kt2 * 128
                                              : xs + a_base + (kt2 - 2) * 128;
#pragma unroll
        for (int j = 0; j < 4; ++j)
            gload16(src + j * 32, &Asm[bb][w * 2048 + j * 512]);
    };
    bf16x8 bfr[4][4];
    auto loadB = [&](int kt2) {
#pragma unroll
        for (int m = 0; m < 4; ++m)
#pragma unroll
            for (int kk = 0; kk < 4; ++kk)
                bfr[m][kk] = *(const bf16x8*)(Wct + (size_t)(2 * kt2 + (kk >> 1)) * 16384
                                              + (size_t)(w * 4 + m) * 1024 + (kk & 1) * 512 + l * 8);
    };

    stageA(0, 0);
    stageA(1, 1);
    loadB(0);

    bf16x8 af[4];
#pragma unroll
    for (int kt2 = 0; kt2 < 4; ++kt2) {
        const int cb = kt2 % 3;
        // outstanding at top: A(kt2) 4 + A(kt2+1) 4 + B(kt2) 16 = 24 -> drain A(kt2)
        if (kt2 < 3) { asm volatile("s_waitcnt vmcnt(20)" ::: "memory"); }
        else         { asm volatile("s_waitcnt vmcnt(16)" ::: "memory"); }
        __builtin_amdgcn_s_barrier();
        __builtin_amdgcn_sched_barrier(0);
        if (kt2 < 2) stageA((kt2 + 2) % 3, kt2 + 2);
#pragma unroll
        for (int kk = 0; kk < 4; ++kk) {
#pragma unroll
            for (int n = 0; n < 4; ++n)
                af[n] = *(const bf16x8*)(&Asm[cb][n * 2048 + kk * 512 + l * 8]);
            __builtin_amdgcn_s_setprio(1);
#pragma unroll
            for (int n = 0; n < 4; ++n)
#pragma unroll
                for (int m = 0; m < 4; ++m)
                    acc[n][m] = __builtin_amdgcn_mfma_f32_16x16x32_bf16(bfr[m][kk], af[n], acc[n][m], 0, 0, 0);
            __builtin_amdgcn_s_setprio(0);
        }
        __builtin_amdgcn_sched_barrier(0);
        if (kt2 < 3) loadB(kt2 + 1);   // bottom-of-iter B prefetch (bfr regs now free)
        asm volatile("s_waitcnt lgkmcnt(0)" ::: "memory");
    }

#pragma unroll
    for (int n = 0; n < 4; ++n) {
        const int grow = row0 + n * 16 + lrow;
        if (grow >= M) continue;
#pragma unroll
        for (int m = 0; m < 4; ++m) {
            const int gcol = w * 64 + m * 16 + slot * 4;
            f32x4 bv = *(const f32x4*)(bias + gcol);
            us4 o;
            o.x = f2bf(fmaxf(acc[n][m][0] + bv.x, 0.f));
            o.y = f2bf(fmaxf(acc[n][m][1] + bv.y, 0.f));
            o.z = f2bf(fmaxf(acc[n][m][2] + bv.z, 0.f));
            o.w = f2bf(fmaxf(acc[n][m][3] + bv.w, 0.f));
            *(us4*)(out + (size_t)grow * 256 + gcol) = o;
        }
    }
}

// ---------------- FUSED layer-2 + fc: out = relu([mean|h]@Wc2^T + bl) @ fcW^T + fcb ----
__global__ __launch_bounds__(256, 3) void k_sage_fc_gemm(const unsigned short* __restrict__ meanb,
                                                         const unsigned short* __restrict__ xs,
                                                         const unsigned short* __restrict__ Wct,
                                                         const float* __restrict__ bias,
                                                         const unsigned short* __restrict__ fcWbt,
                                                         const float* __restrict__ fcb,
                                                         float* __restrict__ out, int M) {
    __shared__ __align__(16) unsigned short pool[24576];   // 48 KB tri-buffer; g-tile aliases first 32 KB
    unsigned short (*Asm)[8192] = (unsigned short(*)[8192])pool;
    const int t = threadIdx.x;
    const int w = t >> 6, l = t & 63;
    const int lrow = l & 15, slot = l >> 4;
    const int row0 = blockIdx.x * 64;

    int a_row = row0 + w * 16 + lrow;
    if (a_row > M - 1) a_row = M - 1;
    const size_t a_base = (size_t)a_row * 256 + slot * 8;

    f32x4 acc[4][4];
#pragma unroll
    for (int n = 0; n < 4; ++n)
#pragma unroll
        for (int m = 0; m < 4; ++m)
#pragma unroll
            for (int j = 0; j < 4; ++j) acc[n][m][j] = 0.0f;

    auto stageA = [&](int bb, int kt2) {
        const unsigned short* src = (kt2 < 2) ? meanb + a_base + kt2 * 128
                                              : xs + a_base + (kt2 - 2) * 128;
#pragma unroll
        for (int j = 0; j < 4; ++j)
            gload16(src + j * 32, &Asm[bb][w * 2048 + j * 512]);
    };
    bf16x8 bfr[4][4];
    auto loadB = [&](int kt2) {
#pragma unroll
        for (int m = 0; m < 4; ++m)
#pragma unroll
            for (int kk = 0; kk < 4; ++kk)
                bfr[m][kk] = *(const bf16x8*)(Wct + (size_t)(2 * kt2 + (kk >> 1)) * 16384
                                              + (size_t)(w * 4 + m) * 1024 + (kk & 1) * 512 + l * 8);
    };

    stageA(0, 0);
    stageA(1, 1);
    loadB(0);

    bf16x8 af[4];
#pragma unroll
    for (int kt2 = 0; kt2 < 4; ++kt2) {
        const int cb = kt2 % 3;
        if (kt2 < 3) { asm volatile("s_waitcnt vmcnt(20)" ::: "memory"); }
        else         { asm volatile("s_waitcnt vmcnt(16)" ::: "memory"); }
        __builtin_amdgcn_s_barrier();
        __builtin_amdgcn_sched_barrier(0);
        if (kt2 < 2) stageA((kt2 + 2) % 3, kt2 + 2);
#pragma unroll
        for (int kk = 0; kk < 4; ++kk) {
#pragma unroll
            for (int n = 0; n < 4; ++n)
                af[n] = *(const bf16x8*)(&Asm[cb][n * 2048 + kk * 512 + l * 8]);
            __builtin_amdgcn_s_setprio(1);
#pragma unroll
            for (int n = 0; n < 4; ++n)
#pragma unroll
                for (int m = 0; m < 4; ++m)
                    acc[n][m] = __builtin_amdgcn_mfma_f32_16x16x32_bf16(bfr[m][kk], af[n], acc[n][m], 0, 0, 0);
            __builtin_amdgcn_s_setprio(0);
        }
        __builtin_amdgcn_sched_barrier(0);
        if (kt2 < 3) loadB(kt2 + 1);
        asm volatile("s_waitcnt lgkmcnt(0)" ::: "memory");
    }

    // g = relu(acc + bias) -> bf16 -> pool (frag-major, conflict-free)
    __syncthreads();
#pragma unroll
    for (int n = 0; n < 4; ++n) {
#pragma unroll
        for (int m = 0; m < 4; ++m) {
            const int gcol = w * 64 + m * 16 + slot * 4;
            f32x4 bv = *(const f32x4*)(bias + gcol);
            us4 o;
            o.x = f2bf(fmaxf(acc[n][m][0] + bv.x, 0.f));
            o.y = f2bf(fmaxf(acc[n][m][1] + bv.y, 0.f));
            o.z = f2bf(fmaxf(acc[n][m][2] + bv.z, 0.f));
            o.w = f2bf(fmaxf(acc[n][m][3] + bv.w, 0.f));
            int addr = w * 4096 + n * 1024 + (m >> 1) * 512
                     + ((((m & 1) * 2 + (slot >> 1)) * 16 + lrow) * 8) + (slot & 1) * 4;
            *(us4*)(&pool[addr]) = o;
        }
    }
    __syncthreads();

    // fc mini-GEMM: out[64x128] = g @ fcW^T + fcb (4 col-tiles of 64 k)
    f32x4 acc2[4][2];
#pragma unroll
    for (int n = 0; n < 4; ++n)
#pragma unroll
        for (int m = 0; m < 2; ++m)
#pragma unroll
            for (int j = 0; j < 4; ++j) acc2[n][m][j] = 0.0f;

#pragma unroll
    for (int kt2 = 0; kt2 < 4; ++kt2) {
        bf16x8 bw[2][2];
#pragma unroll
        for (int m = 0; m < 2; ++m)
#pragma unroll
            for (int kk = 0; kk < 2; ++kk)
                bw[m][kk] = *(const bf16x8*)(fcWbt + (size_t)kt2 * 8192
                                             + (size_t)(w * 2 + m) * 1024 + kk * 512 + l * 8);
#pragma unroll
        for (int kk = 0; kk < 2; ++kk) {
            bf16x8 ag[4];
#pragma unroll
            for (int n = 0; n < 4; ++n)
                ag[n] = *(const bf16x8*)(&pool[kt2 * 4096 + n * 1024 + kk * 512 + l * 8]);
#pragma unroll
            for (int n = 0; n < 4; ++n)
#pragma unroll
                for (int m = 0; m < 2; ++m)
                    acc2[n][m] = __builtin_amdgcn_mfma_f32_16x16x32_bf16(bw[m][kk], ag[n], acc2[n][m], 0, 0, 0);
        }
    }

#pragma unroll
    for (int n = 0; n < 4; ++n) {
        const int grow = row0 + n * 16 + lrow;
        if (grow >= M) continue;
#pragma unroll
        for (int m = 0; m < 2; ++m) {
            const int gcol = w * 32 + m * 16 + slot * 4;
            f32x4 bv = *(const f32x4*)(fcb + gcol);
            f32x4 o;
            o.x = acc2[n][m][0] + bv.x;
            o.y = acc2[n][m][1] + bv.y;
            o.z = acc2[n][m][2] + bv.z;
            o.w = acc2[n][m][3] + bv.w;
            *(f32x4*)(out + (size_t)grow * 128 + gcol) = o;
        }
    }
}

extern "C" void kernel_launch(void* const* d_in, const int* in_sizes, int n_in,
                              void* d_out, int out_size, void* d_ws, size_t ws_size,
                              hipStream_t stream) {
    const float* x_word = (const float*)d_in[0];
    const float* Wl  = (const float*)d_in[3];
    const float* bl  = (const float*)d_in[4];
    const float* Wr  = (const float*)d_in[5];
    const float* fcW = (const float*)d_in[6];
    const float* fcb = (const float*)d_in[7];
    const int* src = (const int*)d_in[8];
    const int* dst = (const int*)d_in[9];

    const int M = in_sizes[0] / 256;   // 200000
    const int E = in_sizes[8];         // 400000
    const int NB = (M + 1023) / 1024;

    char* ws = (char*)d_ws;
    size_t off = 0;
    auto alloc = [&](size_t bytes) {
        void* p = ws + off;
        off = (off + bytes + 255) & ~(size_t)255;
        return p;
    };
    int* cnt_i  = (int*)alloc((size_t)M * 4);
    int* rowptr = (int*)alloc((size_t)(M + 1) * 4);
    int* cursor = (int*)alloc((size_t)M * 4);
    int* eidx   = (int*)alloc((size_t)E * 4);
    int* bsum   = (int*)alloc((size_t)NB * 4);
    unsigned short* xb    = (unsigned short*)alloc((size_t)M * 256 * 2);
    unsigned short* meanb = (unsigned short*)alloc((size_t)M * 256 * 2);
    unsigned short* h     = (unsigned short*)alloc((size_t)M * 256 * 2);
    unsigned short* Wc1   = (unsigned short*)alloc(131072 * 2);
    unsigned short* Wc2   = (unsigned short*)alloc(131072 * 2);
    unsigned short* fcWb  = (unsigned short*)alloc(32768 * 2);

    // fused prep: convx + convw + zero(cnt_i) in ONE launch (they were serializing)
    const int n8 = M * 256 / 8;
    const int nbx = (n8 + 255) / 256;
    const int nbz = (M + 255) / 256;
    k_prep<<<nbx + 1152 + nbz, 256, 0, stream>>>(x_word, xb, n8, nbx,
                                                 Wl, Wr, fcW, Wc1, Wc2, fcWb,
                                                 cnt_i, M);

    // CSR build
    k_hist<<<(E + 255) / 256, 256, 0, stream>>>(dst, cnt_i, E);
    k_bsum<<<NB, 256, 0, stream>>>(cnt_i, bsum, M);
    k_scanb<<<1, 256, 0, stream>>>(bsum, NB, rowptr, M, E);
    k_rowptr<<<NB, 256, 0, stream>>>(cnt_i, bsum, rowptr, cursor, M);
    k_place<<<(E + 255) / 256, 256, 0, stream>>>(src, dst, cursor, eidx, E);

    const int GB = (M + 63) / 64;

    // Layer 1
    k_gather_mean<<<(M + 7) / 8, 256, 0, stream>>>(xb, rowptr, eidx, meanb, M);
    k_sage_gemm<<<GB, 256, 0, stream>>>(meanb, xb, Wc1, bl, h, M);

    // Layer 2 + fc head, fused
    k_gather_mean<<<(M + 7) / 8, 256, 0, stream>>>(h, rowptr, eidx, meanb, M);
    k_sage_fc_gemm<<<GB, 256, 0, stream>>>(meanb, h, Wc2, bl + 3 * 256, fcWb, fcb,
                                           (float*)d_out, M);
}